// Round 20
// baseline (312.073 us; speedup 1.0000x reference)
//
#include <hip/hip_runtime.h>

typedef _Float16 half_t;
typedef half_t h2    __attribute__((ext_vector_type(2)));
typedef half_t half4 __attribute__((ext_vector_type(4)));
typedef half_t half8 __attribute__((ext_vector_type(8)));
typedef __fp16 pk16x2 __attribute__((ext_vector_type(2)));
typedef float  f32x4 __attribute__((ext_vector_type(4)));
typedef float  f32x2 __attribute__((ext_vector_type(2)));
typedef float  f32x16 __attribute__((ext_vector_type(16)));

template <int N> struct IC { static constexpr int value = N; };

static __device__ __forceinline__ half4 pack4(f32x4 a) {
  pk16x2 lo = __builtin_amdgcn_cvt_pkrtz(a[0], a[1]);
  pk16x2 hi = __builtin_amdgcn_cvt_pkrtz(a[2], a[3]);
  half4 h;
  h[0] = lo[0]; h[1] = lo[1]; h[2] = hi[0]; h[3] = hi[1];
  return h;
}

constexpr int B_  = 8;
constexpr int S_  = 15;
constexpr int K_  = 17;
constexpr int P_  = 31;
constexpr int SS_ = 225;
constexpr int PP_ = 961;
constexpr int KK_ = 289;

constexpr int NROW_C = B_ * PP_;          // 7688
constexpr int NROW_T = B_ * SS_;          // 1800
constexpr int NROW   = NROW_C + NROW_T;   // 9488 = 593*16

constexpr int NW0H = 512 * 256;
constexpr int NF16 = 128*256 + 64*128 + 32*64;
constexpr int NFEATB = B_ * 31 + B_ * 8;  // 248 featT blocks

// workspace float offsets
constexpr size_t OFF_GOUT = 0;
constexpr size_t OFF_ROWS = OFF_GOUT + (size_t)NROW * 256;
constexpr size_t OFF_M0   = OFF_ROWS + (size_t)B_ * 31 * 17 * 256;
constexpr size_t OFF_TM0  = OFF_M0   + (size_t)B_ * KK_ * 256;
constexpr size_t OFF_F16  = OFF_TM0  + (size_t)B_ * 256;

// chain LDS byte offsets (53,632 B -> 3 blocks/CU)
constexpr int X0B  = 0;       // f16 x0 [64][512B] swz (x2 aliases; final reduce)
constexpr int X1B  = 32768;   // f16 x1 [64][256B] swz
constexpr int X3TB = 32768;   // f32 x3T [64][36f] (alias dead x1)
constexpr int Y4B  = 41984;   // f32 y4T [64][20f] (alias dead x1)
constexpr int SMB  = 49152;   // 240 f logits
constexpr int REDB = 50112;   // 16 f
constexpr int W4B  = 50176;   // w4 [16][36f]
constexpr int W5B  = 52480;   // w5 [8][20f]
constexpr int W6B  = 53120;   // w6 [8]
constexpr int ROWB = 53152;   // 225 u16 row table
constexpr int LDSB = 53632;

// ---------------------------------------------------------------------------
// fused prep: featT blocks (0..247) + wcvt blocks (248..)
// ---------------------------------------------------------------------------
__global__ __launch_bounds__(256) void prep_kernel(
    const float* __restrict__ templ, const float* __restrict__ cand,
    const float* __restrict__ w0, const float* __restrict__ w1,
    const float* __restrict__ w2, const float* __restrict__ w3,
    half_t* __restrict__ inarrh, half_t* __restrict__ w0h,
    half_t* __restrict__ w1h, half_t* __restrict__ w2h,
    half_t* __restrict__ w3h)
{
  __shared__ float tile[32 * 257];
  const int bid = blockIdx.x;
  const int tid = threadIdx.x;
  if (bid < NFEATB) {
    const float* src;
    int base, npos, rowbase, stride;
    if (bid < B_ * 31) {
      int b = bid / 31, ch = bid % 31;
      src = cand + (size_t)b * 256 * PP_;
      base = ch * 32; npos = min(32, PP_ - base);
      rowbase = b * PP_ + base; stride = PP_;
    } else {
      int t = bid - B_ * 31;
      int b = t / 8, ch = t % 8;
      src = templ + (size_t)b * 256 * SS_;
      base = ch * 32; npos = min(32, SS_ - base);
      rowbase = NROW_C + b * SS_ + base; stride = SS_;
    }
    const int p  = tid & 31;
    const int c8 = tid >> 5;
    if (p < npos) {
      for (int it = 0; it < 32; ++it) {
        int c = c8 * 32 + it;
        tile[p * 257 + c] = src[(size_t)c * stride + base + p];
      }
    }
    __syncthreads();
    for (int pp = 0; pp < npos; ++pp)
      inarrh[(size_t)(rowbase + pp) * 256 + tid] = (half_t)tile[pp * 257 + tid];
  } else {
    const int nb = gridDim.x - NFEATB;
    const int wb = bid - NFEATB;
    const int total = NW0H + NF16;
    for (int idx = wb * 256 + tid; idx < total; idx += nb * 256) {
      if (idx < NW0H) {
        int m = idx >> 8; int c = idx & 255;
        w0h[idx] = (half_t)(m < 256 ? w0[m * 512 + 256 + c] : w0[(m - 256) * 512 + c]);
      } else {
        int t = idx - NW0H;
        if (t < 32768)      w1h[t] = (half_t)w1[t];
        else if (t < 40960) w2h[t - 32768] = (half_t)w2[t - 32768];
        else                w3h[t - 40960] = (half_t)w3[t - 40960];
      }
    }
  }
}

// ---------------------------------------------------------------------------
__global__ __launch_bounds__(512) void l0gemm_kernel(
    const half_t* __restrict__ inh, const half_t* __restrict__ w0h,
    half_t* __restrict__ conv1h, float* __restrict__ gout)
{
  __shared__ __align__(16) char xls[16 * 512];
  const int tid  = threadIdx.x;
  const int lane = tid & 63;
  const int wvs  = tid >> 6;
  const int row0 = blockIdx.x * 16;

  {
    const int row = tid >> 5;
    const int c8  = (tid & 31) * 8;
    half8 h = *(const half8*)(inh + (size_t)(row0 + row) * 256 + c8);
    const int off = (row * 512 + c8 * 2) ^ ((row & 7) << 4);
    *(half8*)(xls + off) = h;
  }
  __syncthreads();

  const int l15 = lane & 15, g = lane >> 4;
  f32x4 acc[4];
#pragma unroll
  for (int mt = 0; mt < 4; ++mt) acc[mt] = (f32x4){0.f, 0.f, 0.f, 0.f};
#pragma unroll 2
  for (int kb = 0; kb < 8; ++kb) {
    const int off = (l15 * 512 + kb * 64 + g * 16) ^ ((l15 & 7) << 4);
    half8 bfr = *(const half8*)(xls + off);
#pragma unroll
    for (int mt = 0; mt < 4; ++mt) {
      const half_t* ap = w0h + (size_t)((wvs * 4 + mt) * 16 + l15) * 256 + kb * 32 + g * 8;
      half8 a = *(const half8*)ap;
      acc[mt] = __builtin_amdgcn_mfma_f32_16x16x32_f16(a, bfr, acc[mt], 0, 0, 0);
    }
  }
#pragma unroll
  for (int mt = 0; mt < 4; ++mt) {
    const int m0c = (wvs * 4 + mt) * 16 + g * 4;
    if (wvs < 4)
      *(half4*)(conv1h + (size_t)(row0 + l15) * 256 + m0c) = pack4(acc[mt]);
    else
      *(f32x4*)(gout + (size_t)(row0 + l15) * 256 + (m0c - 256)) = acc[mt];
  }
}

// ---------------------------------------------------------------------------
__global__ __launch_bounds__(256) void rowsum_kernel(
    const float* __restrict__ gout, float* __restrict__ rows)
{
  const int bid = blockIdx.x;
  const int o = threadIdx.x;
  const int v = bid % 17; const int p = (bid / 17) % 31; const int b = bid / (17 * 31);
  float s = 0.f;
  for (int j = 0; j < 15; ++j)
    s += gout[(size_t)(b * PP_ + p * P_ + v + j) * 256 + o];
  rows[(size_t)bid * 256 + o] = s;
}

__global__ __launch_bounds__(256) void colsum_tmean_kernel(
    const float* __restrict__ rows, const float* __restrict__ gout,
    float* __restrict__ m0v, float* __restrict__ tm0v)
{
  const int bid = blockIdx.x;
  const int o = threadIdx.x;
  if (bid < B_ * KK_) {
    const int v = bid % 17; const int u = (bid / 17) % 17; const int b = bid / KK_;
    float s = 0.f;
    for (int i = 0; i < 15; ++i)
      s += rows[(size_t)((b * 31 + u + i) * 17 + v) * 256 + o];
    m0v[(size_t)bid * 256 + o] = s * (1.0f / 225.0f);
  } else {
    const int b = bid - B_ * KK_;
    float s = 0.f;
    for (int t = 0; t < SS_; ++t)
      s += gout[(size_t)(NROW_C + b * SS_ + t) * 256 + o];
    tm0v[b * 256 + o] = s * (1.0f / 225.0f);
  }
}

// ---------------------------------------------------------------------------
__global__ __launch_bounds__(512, 4) void chain_kernel(
    const half_t* __restrict__ conv1h, const float* __restrict__ m0v,
    const float* __restrict__ tm0v,
    const half_t* __restrict__ w1h, const half_t* __restrict__ w2h,
    const half_t* __restrict__ w3h,
    const float* __restrict__ w4, const float* __restrict__ w5,
    const float* __restrict__ w6,
    const half_t* __restrict__ inarrh, float* __restrict__ out)
{
  __shared__ __align__(16) char lds[LDSB];
  float*    ldsf   = (float*)lds;
  float*    sm     = (float*)(lds + SMB);
  float*    red    = (float*)(lds + REDB);
  uint16_t* rowoff = (uint16_t*)(lds + ROWB);

  const int tid  = threadIdx.x;
  const int lane = tid & 63;
  const int wvs  = __builtin_amdgcn_readfirstlane(tid >> 6);
  const int bid  = (blockIdx.x & 7) * 290 + (blockIdx.x >> 3);
  const bool is_t = (bid >= B_ * KK_);
  int b, u = 0, v = 0;
  const float* mean_vec;
  if (!is_t) {
    b = bid / KK_;
    int r = bid % KK_;
    u = r / K_; v = r % K_;
    mean_vec = m0v + (size_t)bid * 256;
  } else {
    b = bid - B_ * KK_;
    mean_vec = tm0v + (size_t)b * 256;
  }

  if (tid < SS_) {
    int i = tid / 15, j = tid - i * 15;
    rowoff[tid] = is_t ? (uint16_t)(NROW_C + b * SS_ + tid)
                       : (uint16_t)(b * PP_ + (u + i) * P_ + (v + j));
  }
  ((float*)(lds + W4B))[(tid >> 5) * 36 + (tid & 31)] = w4[tid];
  if (tid < 128) ((float*)(lds + W5B))[(tid >> 4) * 20 + (tid & 15)] = w5[tid];
  if (tid < 8)   ((float*)(lds + W6B))[tid] = w6[tid];

  const int l31 = lane & 31;
  const int lhi = lane >> 5;
  // L1 32x32x16 wave mapping: ct = out-ch tile (32), pt = pos tile (32)
  const int ct1 = wvs & 3, pt1 = wvs >> 2;
  const half_t* w1b32 = w1h + (size_t)(32 * ct1 + l31) * 256 + lhi * 8;
  const int g2 = wvs & 3, h2w = wvs >> 2;
  half8 af2[4];
  {
    const half_t* base = w2h + (size_t)(16 * g2 + (lane & 15)) * 128 + ((lane >> 4) << 3);
#pragma unroll
    for (int kb = 0; kb < 4; ++kb) af2[kb] = *(const half8*)(base + kb * 32);
  }
  const int rt3 = wvs & 1, ct3 = wvs >> 1;
  const half_t* b3ptr = w3h + (size_t)(16 * rt3 + (lane & 15)) * 64 + ((lane >> 4) << 3);
  const int c8  = l31 * 8;
  half8 mvh;
  {
    f32x4 ma = *(const f32x4*)(mean_vec + c8);
    f32x4 mb = *(const f32x4*)(mean_vec + c8 + 4);
    half4 h0 = pack4(ma), h1 = pack4(mb);
#pragma unroll
    for (int r = 0; r < 4; ++r) { mvh[r] = h0[r]; mvh[4 + r] = h1[r]; }
  }
  __syncthreads();   // rowoff visibility

  auto ldcv = [&](int s) -> half8 {
    return *(const half8*)(conv1h + ((size_t)rowoff[min(s, SS_ - 1)] << 8) + c8);
  };
  auto stage_write = [&](int pos, half8 cv) {
    half8 t = cv + mvh;
    half8 s2 = t * (half_t)0.01f;
    half8 r8 = __builtin_elementwise_max(t, s2);
    const int off = (pos * 512 + c8 * 2) ^ ((pos & 7) << 4);
    *(half8*)(lds + X0B + off) = r8;
  };

  // prologue: stage tile 0 (64 pos)
  {
    const int pbase = 8 * wvs + lhi;
#pragma unroll
    for (int it = 0; it < 4; ++it)
      stage_write(pbase + it * 2, ldcv(pbase + it * 2));
  }
  __syncthreads();

  // tile body; NPOS = live positions this tile (guards on L2/L3 writes)
  auto process = [&](auto nposc, int ti, int nnext) {
    constexpr int NPOS = decltype(nposc)::value;
    const int s0 = ti * 64;
    const int cnt = min(64, SS_ - s0);

    // ---- layer 1: 256 -> 128, 32x32x16 MFMA (wave = 32ch x 32pos), W1 streamed
    {
      f32x16 acc;
#pragma unroll
      for (int i = 0; i < 16; ++i) acc[i] = 0.f;
      const half_t* w1p = w1b32;
      asm volatile("" : "+v"(w1p));
      const int pos = 32 * pt1 + l31;
#pragma unroll 2
      for (int kb = 0; kb < 16; ++kb) {
        half8 a1 = *(const half8*)(w1p + kb * 16);
        const int off = (pos * 512 + kb * 32 + lhi * 16) ^ ((pos & 7) << 4);
        half8 bfr = *(const half8*)(lds + X0B + off);
        acc = __builtin_amdgcn_mfma_f32_32x32x16_f16(a1, bfr, acc, 0, 0, 0);
      }
#pragma unroll
      for (int q = 0; q < 4; ++q) {
        f32x4 a;
        a[0] = acc[4 * q];     a[1] = acc[4 * q + 1];
        a[2] = acc[4 * q + 2]; a[3] = acc[4 * q + 3];
#pragma unroll
        for (int r = 0; r < 4; ++r) a[r] = fmaxf(a[r], 0.01f * a[r]);
        const int ch0 = 32 * ct1 + 8 * q + 4 * lhi;
        const int off = (pos * 256 + ch0 * 2) ^ ((pos & 7) << 4);
        *(half4*)(lds + X1B + off) = pack4(a);
      }
    }
    __syncthreads();

    // ---- layer 2: 128 -> 64 MFMA; write x2 guarded to pos<NPOS
    f32x4 acc2[2];
#pragma unroll
    for (int nt = 0; nt < 2; ++nt) acc2[nt] = (f32x4){0.f, 0.f, 0.f, 0.f};
#pragma unroll
    for (int kb = 0; kb < 4; ++kb) {
      const int kbyte = kb * 64 + ((lane >> 4) << 4);
#pragma unroll
      for (int nt = 0; nt < 2; ++nt) {
        const int pos = h2w * 32 + nt * 16 + (lane & 15);
        const int off = (pos * 256 + kbyte) ^ ((pos & 7) << 4);
        half8 bfr = *(const half8*)(lds + X1B + off);
        acc2[nt] = __builtin_amdgcn_mfma_f32_16x16x32_f16(af2[kb], bfr, acc2[nt], 0, 0, 0);
      }
    }
#pragma unroll
    for (int nt = 0; nt < 2; ++nt) {
      const int pos = h2w * 32 + nt * 16 + (lane & 15);
      const int ch0 = 16 * g2 + ((lane >> 4) << 2);
      f32x4 a;
#pragma unroll
      for (int r = 0; r < 4; ++r) a[r] = fmaxf(acc2[nt][r], 0.01f * acc2[nt][r]);
      const int off = (pos * 128 + ch0 * 2) ^ ((pos & 7) << 4);
      if constexpr (NPOS < 64) {
        if (pos < NPOS) *(half4*)(lds + X0B + off) = pack4(a);
      } else {
        *(half4*)(lds + X0B + off) = pack4(a);
      }
    }
    __syncthreads();

    // ---- layer 3 phase: cv prefetch (next tile) + L3 MFMA
    half8 cv0, cv1, cv2, cv3;
    const int npw = nnext >> 3;              // 8 or 6 (or 0)
    const int pb = npw * wvs + lhi;
    if (nnext) {
      const int s1 = s0 + 64;
      cv0 = ldcv(s1 + pb);
      cv1 = ldcv(s1 + pb + 2);
      cv2 = ldcv(s1 + pb + 4);
      if (nnext == 64) cv3 = ldcv(s1 + pb + 6);
    }
    {
      f32x4 acc3 = (f32x4){0.f, 0.f, 0.f, 0.f};
      const int pos = ct3 * 16 + (lane & 15);
#pragma unroll
      for (int kb = 0; kb < 2; ++kb) {
        half8 a3 = *(const half8*)(b3ptr + kb * 32);
        const int kbyte = kb * 64 + ((lane >> 4) << 4);
        const int off = (pos * 128 + kbyte) ^ ((pos & 7) << 4);
        half8 bfr = *(const half8*)(lds + X0B + off);
        acc3 = __builtin_amdgcn_mfma_f32_16x16x32_f16(a3, bfr, acc3, 0, 0, 0);
      }
      const int ch0 = 16 * rt3 + ((lane >> 4) << 2);
      f32x4 o4;
#pragma unroll
      for (int r = 0; r < 4; ++r) o4[r] = fmaxf(acc3[r], 0.01f * acc3[r]);
      if constexpr (NPOS < 64) {
        if (pos < NPOS) *(f32x4*)(lds + X3TB + pos * 144 + ch0 * 4) = o4;
      } else {
        *(f32x4*)(lds + X3TB + pos * 144 + ch0 * 4) = o4;
      }
    }
    __syncthreads();

    // ---- tail (layers 4-6) + stage writes for next tile
    {
      const int p = lane >> 3, g = lane & 7;
      const int pos = 8 * wvs + p;
      float a4_0 = 0.f, a4_1 = 0.f;
#pragma unroll
      for (int c0 = 0; c0 < 32; c0 += 4) {
        f32x4 x  = *(const f32x4*)(lds + X3TB + pos * 144 + c0 * 4);
        f32x4 wA = *(const f32x4*)(lds + W4B + (2 * g) * 144 + c0 * 4);
        f32x4 wB = *(const f32x4*)(lds + W4B + (2 * g + 1) * 144 + c0 * 4);
#pragma unroll
        for (int r = 0; r < 4; ++r) {
          a4_0 = fmaf(wA[r], x[r], a4_0);
          a4_1 = fmaf(wB[r], x[r], a4_1);
        }
      }
      f32x2 y4v;
      y4v[0] = fmaxf(a4_0, 0.01f * a4_0);
      y4v[1] = fmaxf(a4_1, 0.01f * a4_1);
      *(f32x2*)(lds + Y4B + pos * 80 + g * 8) = y4v;
      float a5 = 0.f;
#pragma unroll
      for (int c0 = 0; c0 < 16; c0 += 4) {
        f32x4 x = *(const f32x4*)(lds + Y4B + pos * 80 + c0 * 4);
        f32x4 w = *(const f32x4*)(lds + W5B + g * 80 + c0 * 4);
#pragma unroll
        for (int r = 0; r < 4; ++r) a5 = fmaf(w[r], x[r], a5);
      }
      a5 = fmaxf(a5, 0.01f * a5);
      float t6 = ((float*)(lds + W6B))[g] * a5;
      t6 += __shfl_xor(t6, 1);
      t6 += __shfl_xor(t6, 2);
      t6 += __shfl_xor(t6, 4);
      if (g == 0 && pos < cnt) sm[s0 + pos] = t6;

      if (nnext) {
        stage_write(pb,     cv0);
        stage_write(pb + 2, cv1);
        stage_write(pb + 4, cv2);
        if (nnext == 64) stage_write(pb + 6, cv3);
      }
    }
    __syncthreads();
  };

  process(IC<64>{}, 0, 64);
  process(IC<64>{}, 1, 64);
  process(IC<64>{}, 2, 48);
  process(IC<48>{}, 3, 0);

  // ---- softmax over 225 logits
  float vv = (tid < SS_) ? sm[tid] : -1e30f;
  float m = vv;
#pragma unroll
  for (int off = 32; off >= 1; off >>= 1) m = fmaxf(m, __shfl_xor(m, off));
  if (lane == 0) red[wvs] = m;
  __syncthreads();
  m = red[0];
#pragma unroll
  for (int w = 1; w < 8; ++w) m = fmaxf(m, red[w]);
  float e = (tid < SS_) ? __expf(vv - m) : 0.f;
  float ss = e;
#pragma unroll
  for (int off = 32; off >= 1; off >>= 1) ss += __shfl_xor(ss, off);
  __syncthreads();
  if (lane == 0) red[wvs] = ss;
  __syncthreads();
  float Stot = red[0];
#pragma unroll
  for (int w = 1; w < 8; ++w) Stot += red[w];
  if (tid < SS_) sm[tid] = e / Stot;
  __syncthreads();

  // ---- weighted channel sum: 2 channels/thread (f16 features), 4-way pos split
  {
    const int c2 = (tid & 127) * 2;
    const int q  = tid >> 7;
    float accx = 0.f, accy = 0.f;
    for (int s = q; s < SS_; s += 4) {
      h2 ft = *(const h2*)(inarrh + ((size_t)rowoff[s] << 8) + c2);
      float w = sm[s];
      accx = fmaf(w, (float)ft[0], accx);
      accy = fmaf(w, (float)ft[1], accy);
    }
    __syncthreads();
    ldsf[q * 256 + c2]     = accx;
    ldsf[q * 256 + c2 + 1] = accy;
    __syncthreads();
    if (tid < 256) {
      float tot = ldsf[tid] + ldsf[256 + tid] + ldsf[512 + tid] + ldsf[768 + tid];
      if (!is_t) out[2048 + ((size_t)(b * 256 + tid) * 17 + u) * 17 + v] = tot;
      else       out[b * 256 + tid] = tot;
    }
  }
}

// ---------------------------------------------------------------------------
extern "C" void kernel_launch(void* const* d_in, const int* in_sizes, int n_in,
                              void* d_out, int out_size, void* d_ws, size_t ws_size,
                              hipStream_t stream)
{
  const float* templ = (const float*)d_in[0];
  const float* cand  = (const float*)d_in[1];
  const float* w0 = (const float*)d_in[2];
  const float* w1 = (const float*)d_in[3];
  const float* w2 = (const float*)d_in[4];
  const float* w3 = (const float*)d_in[5];
  const float* w4 = (const float*)d_in[6];
  const float* w5 = (const float*)d_in[7];
  const float* w6 = (const float*)d_in[8];

  float* ws    = (float*)d_ws;
  float* gout  = ws + OFF_GOUT;
  float* rows  = ws + OFF_ROWS;
  float* m0v   = ws + OFF_M0;
  float* tm0v  = ws + OFF_TM0;
  half_t* inarrh = (half_t*)(ws + OFF_F16);
  half_t* conv1h = inarrh + (size_t)NROW * 256;
  half_t* w0h  = conv1h + (size_t)NROW * 256;
  half_t* w1h  = w0h + NW0H;
  half_t* w2h  = w1h + 128 * 256;
  half_t* w3h  = w2h + 64 * 128;
  float* outf  = (float*)d_out;

  prep_kernel<<<NFEATB + 88, 256, 0, stream>>>(templ, cand, w0, w1, w2, w3,
                                               inarrh, w0h, w1h, w2h, w3h);
  l0gemm_kernel<<<NROW / 16, 512, 0, stream>>>(inarrh, w0h, conv1h, gout);
  rowsum_kernel<<<B_ * 31 * 17, 256, 0, stream>>>(gout, rows);
  colsum_tmean_kernel<<<B_ * KK_ + B_, 256, 0, stream>>>(rows, gout, m0v, tm0v);
  chain_kernel<<<B_ * KK_ + B_, 512, 0, stream>>>(conv1h, m0v, tm0v,
                                                  w1h, w2h, w3h, w4, w5, w6,
                                                  inarrh, outf);
}

// Round 21
// 251.008 us; speedup vs baseline: 1.2433x; 1.2433x over previous
//
#include <hip/hip_runtime.h>

typedef _Float16 half_t;
typedef half_t h2    __attribute__((ext_vector_type(2)));
typedef half_t half4 __attribute__((ext_vector_type(4)));
typedef half_t half8 __attribute__((ext_vector_type(8)));
typedef __fp16 pk16x2 __attribute__((ext_vector_type(2)));
typedef float  f32x4 __attribute__((ext_vector_type(4)));
typedef float  f32x2 __attribute__((ext_vector_type(2)));

template <int N> struct IC { static constexpr int value = N; };

static __device__ __forceinline__ half4 pack4(f32x4 a) {
  pk16x2 lo = __builtin_amdgcn_cvt_pkrtz(a[0], a[1]);
  pk16x2 hi = __builtin_amdgcn_cvt_pkrtz(a[2], a[3]);
  half4 h;
  h[0] = lo[0]; h[1] = lo[1]; h[2] = hi[0]; h[3] = hi[1];
  return h;
}

constexpr int B_  = 8;
constexpr int S_  = 15;
constexpr int K_  = 17;
constexpr int P_  = 31;
constexpr int SS_ = 225;
constexpr int PP_ = 961;
constexpr int KK_ = 289;

constexpr int NROW_C = B_ * PP_;          // 7688
constexpr int NROW_T = B_ * SS_;          // 1800
constexpr int NROW   = NROW_C + NROW_T;   // 9488 = 593*16

constexpr int NW0H = 512 * 256;
constexpr int NF16 = 128*256 + 64*128 + 32*64;
constexpr int NFEATB = B_ * 31 + B_ * 8;  // 248 featT blocks

// workspace float offsets
constexpr size_t OFF_GOUT = 0;
constexpr size_t OFF_ROWS = OFF_GOUT + (size_t)NROW * 256;
constexpr size_t OFF_M0   = OFF_ROWS + (size_t)B_ * 31 * 17 * 256;
constexpr size_t OFF_TM0  = OFF_M0   + (size_t)B_ * KK_ * 256;
constexpr size_t OFF_F16  = OFF_TM0  + (size_t)B_ * 256;

// chain LDS byte offsets (53,632 B -> 3 blocks/CU)
constexpr int X0B  = 0;       // f16 x0 [64][512B] swz (x2 aliases; final reduce)
constexpr int X1B  = 32768;   // f16 x1 [64][256B] swz
constexpr int X3TB = 32768;   // f32 x3T [64][36f] (alias dead x1)
constexpr int Y4B  = 41984;   // f32 y4T [64][20f] (alias dead x1)
constexpr int SMB  = 49152;   // 240 f logits
constexpr int REDB = 50112;   // 16 f
constexpr int W4B  = 50176;   // w4 [16][36f]
constexpr int W5B  = 52480;   // w5 [8][20f]
constexpr int W6B  = 53120;   // w6 [8]
constexpr int ROWB = 53152;   // 225 u16 row table
constexpr int LDSB = 53632;

// ---------------------------------------------------------------------------
// fused prep: featT blocks (0..247) + wcvt blocks (248..)
// ---------------------------------------------------------------------------
__global__ __launch_bounds__(256) void prep_kernel(
    const float* __restrict__ templ, const float* __restrict__ cand,
    const float* __restrict__ w0, const float* __restrict__ w1,
    const float* __restrict__ w2, const float* __restrict__ w3,
    half_t* __restrict__ inarrh, half_t* __restrict__ w0h,
    half_t* __restrict__ w1h, half_t* __restrict__ w2h,
    half_t* __restrict__ w3h)
{
  __shared__ float tile[32 * 257];
  const int bid = blockIdx.x;
  const int tid = threadIdx.x;
  if (bid < NFEATB) {
    const float* src;
    int base, npos, rowbase, stride;
    if (bid < B_ * 31) {
      int b = bid / 31, ch = bid % 31;
      src = cand + (size_t)b * 256 * PP_;
      base = ch * 32; npos = min(32, PP_ - base);
      rowbase = b * PP_ + base; stride = PP_;
    } else {
      int t = bid - B_ * 31;
      int b = t / 8, ch = t % 8;
      src = templ + (size_t)b * 256 * SS_;
      base = ch * 32; npos = min(32, SS_ - base);
      rowbase = NROW_C + b * SS_ + base; stride = SS_;
    }
    const int p  = tid & 31;
    const int c8 = tid >> 5;
    if (p < npos) {
      for (int it = 0; it < 32; ++it) {
        int c = c8 * 32 + it;
        tile[p * 257 + c] = src[(size_t)c * stride + base + p];
      }
    }
    __syncthreads();
    for (int pp = 0; pp < npos; ++pp)
      inarrh[(size_t)(rowbase + pp) * 256 + tid] = (half_t)tile[pp * 257 + tid];
  } else {
    const int nb = gridDim.x - NFEATB;
    const int wb = bid - NFEATB;
    const int total = NW0H + NF16;
    for (int idx = wb * 256 + tid; idx < total; idx += nb * 256) {
      if (idx < NW0H) {
        int m = idx >> 8; int c = idx & 255;
        w0h[idx] = (half_t)(m < 256 ? w0[m * 512 + 256 + c] : w0[(m - 256) * 512 + c]);
      } else {
        int t = idx - NW0H;
        if (t < 32768)      w1h[t] = (half_t)w1[t];
        else if (t < 40960) w2h[t - 32768] = (half_t)w2[t - 32768];
        else                w3h[t - 40960] = (half_t)w3[t - 40960];
      }
    }
  }
}

// ---------------------------------------------------------------------------
__global__ __launch_bounds__(512) void l0gemm_kernel(
    const half_t* __restrict__ inh, const half_t* __restrict__ w0h,
    half_t* __restrict__ conv1h, float* __restrict__ gout)
{
  __shared__ __align__(16) char xls[16 * 512];
  const int tid  = threadIdx.x;
  const int lane = tid & 63;
  const int wvs  = tid >> 6;
  const int row0 = blockIdx.x * 16;

  {
    const int row = tid >> 5;
    const int c8  = (tid & 31) * 8;
    half8 h = *(const half8*)(inh + (size_t)(row0 + row) * 256 + c8);
    const int off = (row * 512 + c8 * 2) ^ ((row & 7) << 4);
    *(half8*)(xls + off) = h;
  }
  __syncthreads();

  const int l15 = lane & 15, g = lane >> 4;
  f32x4 acc[4];
#pragma unroll
  for (int mt = 0; mt < 4; ++mt) acc[mt] = (f32x4){0.f, 0.f, 0.f, 0.f};
#pragma unroll 2
  for (int kb = 0; kb < 8; ++kb) {
    const int off = (l15 * 512 + kb * 64 + g * 16) ^ ((l15 & 7) << 4);
    half8 bfr = *(const half8*)(xls + off);
#pragma unroll
    for (int mt = 0; mt < 4; ++mt) {
      const half_t* ap = w0h + (size_t)((wvs * 4 + mt) * 16 + l15) * 256 + kb * 32 + g * 8;
      half8 a = *(const half8*)ap;
      acc[mt] = __builtin_amdgcn_mfma_f32_16x16x32_f16(a, bfr, acc[mt], 0, 0, 0);
    }
  }
#pragma unroll
  for (int mt = 0; mt < 4; ++mt) {
    const int m0c = (wvs * 4 + mt) * 16 + g * 4;
    if (wvs < 4)
      *(half4*)(conv1h + (size_t)(row0 + l15) * 256 + m0c) = pack4(acc[mt]);
    else
      *(f32x4*)(gout + (size_t)(row0 + l15) * 256 + (m0c - 256)) = acc[mt];
  }
}

// ---------------------------------------------------------------------------
__global__ __launch_bounds__(256) void rowsum_kernel(
    const float* __restrict__ gout, float* __restrict__ rows)
{
  const int bid = blockIdx.x;
  const int o = threadIdx.x;
  const int v = bid % 17; const int p = (bid / 17) % 31; const int b = bid / (17 * 31);
  float s = 0.f;
  for (int j = 0; j < 15; ++j)
    s += gout[(size_t)(b * PP_ + p * P_ + v + j) * 256 + o];
  rows[(size_t)bid * 256 + o] = s;
}

__global__ __launch_bounds__(256) void colsum_tmean_kernel(
    const float* __restrict__ rows, const float* __restrict__ gout,
    float* __restrict__ m0v, float* __restrict__ tm0v)
{
  const int bid = blockIdx.x;
  const int o = threadIdx.x;
  if (bid < B_ * KK_) {
    const int v = bid % 17; const int u = (bid / 17) % 17; const int b = bid / KK_;
    float s = 0.f;
    for (int i = 0; i < 15; ++i)
      s += rows[(size_t)((b * 31 + u + i) * 17 + v) * 256 + o];
    m0v[(size_t)bid * 256 + o] = s * (1.0f / 225.0f);
  } else {
    const int b = bid - B_ * KK_;
    float s = 0.f;
    for (int t = 0; t < SS_; ++t)
      s += gout[(size_t)(NROW_C + b * SS_ + t) * 256 + o];
    tm0v[b * 256 + o] = s * (1.0f / 225.0f);
  }
}

// ---------------------------------------------------------------------------
__global__ __launch_bounds__(512, 4) void chain_kernel(
    const half_t* __restrict__ conv1h, const float* __restrict__ m0v,
    const float* __restrict__ tm0v,
    const half_t* __restrict__ w1h, const half_t* __restrict__ w2h,
    const half_t* __restrict__ w3h,
    const float* __restrict__ w4, const float* __restrict__ w5,
    const float* __restrict__ w6,
    const half_t* __restrict__ inarrh, float* __restrict__ out)
{
  __shared__ __align__(16) char lds[LDSB];
  float*    ldsf   = (float*)lds;
  float*    sm     = (float*)(lds + SMB);
  float*    red    = (float*)(lds + REDB);
  uint16_t* rowoff = (uint16_t*)(lds + ROWB);

  const int tid  = threadIdx.x;
  const int lane = tid & 63;
  const int wvs  = __builtin_amdgcn_readfirstlane(tid >> 6);
  const int bid  = (blockIdx.x & 7) * 290 + (blockIdx.x >> 3);
  const bool is_t = (bid >= B_ * KK_);
  int b, u = 0, v = 0;
  const float* mean_vec;
  if (!is_t) {
    b = bid / KK_;
    int r = bid % KK_;
    u = r / K_; v = r % K_;
    mean_vec = m0v + (size_t)bid * 256;
  } else {
    b = bid - B_ * KK_;
    mean_vec = tm0v + (size_t)b * 256;
  }

  if (tid < SS_) {
    int i = tid / 15, j = tid - i * 15;
    rowoff[tid] = is_t ? (uint16_t)(NROW_C + b * SS_ + tid)
                       : (uint16_t)(b * PP_ + (u + i) * P_ + (v + j));
  }
  ((float*)(lds + W4B))[(tid >> 5) * 36 + (tid & 31)] = w4[tid];
  if (tid < 128) ((float*)(lds + W5B))[(tid >> 4) * 20 + (tid & 15)] = w5[tid];
  if (tid < 8)   ((float*)(lds + W6B))[tid] = w6[tid];

  const half_t* w1base = w1h + (size_t)(16 * wvs + (lane & 15)) * 256 + ((lane >> 4) << 3);
  const int g2 = wvs & 3, h2w = wvs >> 2;
  half8 af2[4];
  {
    const half_t* base = w2h + (size_t)(16 * g2 + (lane & 15)) * 128 + ((lane >> 4) << 3);
#pragma unroll
    for (int kb = 0; kb < 4; ++kb) af2[kb] = *(const half8*)(base + kb * 32);
  }
  const int rt3 = wvs & 1, ct3 = wvs >> 1;
  const half_t* b3ptr = w3h + (size_t)(16 * rt3 + (lane & 15)) * 64 + ((lane >> 4) << 3);
  const int c8  = (lane & 31) * 8;
  const int lhi = lane >> 5;
  half8 mvh;
  {
    f32x4 ma = *(const f32x4*)(mean_vec + c8);
    f32x4 mb = *(const f32x4*)(mean_vec + c8 + 4);
    half4 h0 = pack4(ma), h1 = pack4(mb);
#pragma unroll
    for (int r = 0; r < 4; ++r) { mvh[r] = h0[r]; mvh[4 + r] = h1[r]; }
  }
  __syncthreads();   // rowoff visibility

  auto ldcv = [&](int s) -> half8 {
    return *(const half8*)(conv1h + ((size_t)rowoff[min(s, SS_ - 1)] << 8) + c8);
  };
  auto stage_write = [&](int pos, half8 cv) {
    half8 t = cv + mvh;
    half8 s2 = t * (half_t)0.01f;
    half8 r8 = __builtin_elementwise_max(t, s2);
    const int off = (pos * 512 + c8 * 2) ^ ((pos & 7) << 4);
    *(half8*)(lds + X0B + off) = r8;
  };

  // prologue: stage tile 0 (64 pos)
  {
    const int pbase = 8 * wvs + lhi;
#pragma unroll
    for (int it = 0; it < 4; ++it)
      stage_write(pbase + it * 2, ldcv(pbase + it * 2));
  }
  __syncthreads();

  // tile body, templated on NPOS (this tile's live positions, mult of 16)
  auto process = [&](auto nposc, int ti, int nnext) {
    constexpr int NPOS = decltype(nposc)::value;
    constexpr int NT = NPOS / 16;
    const int s0 = ti * 64;
    const int cnt = min(64, SS_ - s0);

    // ---- layer 1: 256 -> NT*16 pos MFMA, W1 streamed (4 independent chains)
    f32x4 acc[NT];
#pragma unroll
    for (int nt = 0; nt < NT; ++nt) acc[nt] = (f32x4){0.f, 0.f, 0.f, 0.f};
    {
      const half_t* w1p = w1base;
      asm volatile("" : "+v"(w1p));
#pragma unroll 2
      for (int kb = 0; kb < 8; ++kb) {
        half8 a1 = *(const half8*)(w1p + kb * 32);
        const int kbyte = kb * 64 + ((lane >> 4) << 4);
#pragma unroll
        for (int nt = 0; nt < NT; ++nt) {
          const int pos = nt * 16 + (lane & 15);
          const int off = (pos * 512 + kbyte) ^ ((pos & 7) << 4);
          half8 bfr = *(const half8*)(lds + X0B + off);
          acc[nt] = __builtin_amdgcn_mfma_f32_16x16x32_f16(a1, bfr, acc[nt], 0, 0, 0);
        }
      }
#pragma unroll
      for (int nt = 0; nt < NT; ++nt) {
        const int pos = nt * 16 + (lane & 15);
        f32x4 a;
#pragma unroll
        for (int r = 0; r < 4; ++r) a[r] = fmaxf(acc[nt][r], 0.01f * acc[nt][r]);
        const int ch0 = 16 * wvs + ((lane >> 4) << 2);
        const int off = (pos * 256 + ch0 * 2) ^ ((pos & 7) << 4);
        *(half4*)(lds + X1B + off) = pack4(a);
      }
    }
    __syncthreads();

    // ---- layer 2: 128 -> 64 MFMA; write x2 guarded to pos<NPOS
    f32x4 acc2[2];
#pragma unroll
    for (int nt = 0; nt < 2; ++nt) acc2[nt] = (f32x4){0.f, 0.f, 0.f, 0.f};
#pragma unroll
    for (int kb = 0; kb < 4; ++kb) {
      const int kbyte = kb * 64 + ((lane >> 4) << 4);
#pragma unroll
      for (int nt = 0; nt < 2; ++nt) {
        const int pos = h2w * 32 + nt * 16 + (lane & 15);
        const int off = (pos * 256 + kbyte) ^ ((pos & 7) << 4);
        half8 bfr = *(const half8*)(lds + X1B + off);
        acc2[nt] = __builtin_amdgcn_mfma_f32_16x16x32_f16(af2[kb], bfr, acc2[nt], 0, 0, 0);
      }
    }
#pragma unroll
    for (int nt = 0; nt < 2; ++nt) {
      const int pos = h2w * 32 + nt * 16 + (lane & 15);
      const int ch0 = 16 * g2 + ((lane >> 4) << 2);
      f32x4 a;
#pragma unroll
      for (int r = 0; r < 4; ++r) a[r] = fmaxf(acc2[nt][r], 0.01f * acc2[nt][r]);
      const int off = (pos * 128 + ch0 * 2) ^ ((pos & 7) << 4);
      if constexpr (NPOS < 64) {
        if (pos < NPOS) *(half4*)(lds + X0B + off) = pack4(a);
      } else {
        *(half4*)(lds + X0B + off) = pack4(a);
      }
    }
    __syncthreads();

    // ---- layer 3 phase: cv prefetch (next tile) + L3 MFMA
    half8 cv0, cv1, cv2, cv3;
    const int npw = nnext >> 3;              // 8 or 6 (or 0)
    const int pb = npw * wvs + lhi;
    if (nnext) {
      const int s1 = s0 + 64;
      cv0 = ldcv(s1 + pb);
      cv1 = ldcv(s1 + pb + 2);
      cv2 = ldcv(s1 + pb + 4);
      if (nnext == 64) cv3 = ldcv(s1 + pb + 6);
    }
    {
      f32x4 acc3 = (f32x4){0.f, 0.f, 0.f, 0.f};
      const int pos = ct3 * 16 + (lane & 15);
#pragma unroll
      for (int kb = 0; kb < 2; ++kb) {
        half8 a3 = *(const half8*)(b3ptr + kb * 32);
        const int kbyte = kb * 64 + ((lane >> 4) << 4);
        const int off = (pos * 128 + kbyte) ^ ((pos & 7) << 4);
        half8 bfr = *(const half8*)(lds + X0B + off);
        acc3 = __builtin_amdgcn_mfma_f32_16x16x32_f16(a3, bfr, acc3, 0, 0, 0);
      }
      const int ch0 = 16 * rt3 + ((lane >> 4) << 2);
      f32x4 o4;
#pragma unroll
      for (int r = 0; r < 4; ++r) o4[r] = fmaxf(acc3[r], 0.01f * acc3[r]);
      if constexpr (NPOS < 64) {
        if (pos < NPOS) *(f32x4*)(lds + X3TB + pos * 144 + ch0 * 4) = o4;
      } else {
        *(f32x4*)(lds + X3TB + pos * 144 + ch0 * 4) = o4;
      }
    }
    __syncthreads();

    // ---- tail (layers 4-6) + stage writes for next tile
    {
      const int p = lane >> 3, g = lane & 7;
      const int pos = 8 * wvs + p;
      float a4_0 = 0.f, a4_1 = 0.f;
#pragma unroll
      for (int c0 = 0; c0 < 32; c0 += 4) {
        f32x4 x  = *(const f32x4*)(lds + X3TB + pos * 144 + c0 * 4);
        f32x4 wA = *(const f32x4*)(lds + W4B + (2 * g) * 144 + c0 * 4);
        f32x4 wB = *(const f32x4*)(lds + W4B + (2 * g + 1) * 144 + c0 * 4);
#pragma unroll
        for (int r = 0; r < 4; ++r) {
          a4_0 = fmaf(wA[r], x[r], a4_0);
          a4_1 = fmaf(wB[r], x[r], a4_1);
        }
      }
      f32x2 y4v;
      y4v[0] = fmaxf(a4_0, 0.01f * a4_0);
      y4v[1] = fmaxf(a4_1, 0.01f * a4_1);
      *(f32x2*)(lds + Y4B + pos * 80 + g * 8) = y4v;
      float a5 = 0.f;
#pragma unroll
      for (int c0 = 0; c0 < 16; c0 += 4) {
        f32x4 x = *(const f32x4*)(lds + Y4B + pos * 80 + c0 * 4);
        f32x4 w = *(const f32x4*)(lds + W5B + g * 80 + c0 * 4);
#pragma unroll
        for (int r = 0; r < 4; ++r) a5 = fmaf(w[r], x[r], a5);
      }
      a5 = fmaxf(a5, 0.01f * a5);
      float t6 = ((float*)(lds + W6B))[g] * a5;
      t6 += __shfl_xor(t6, 1);
      t6 += __shfl_xor(t6, 2);
      t6 += __shfl_xor(t6, 4);
      if (g == 0 && pos < cnt) sm[s0 + pos] = t6;

      if (nnext) {
        stage_write(pb,     cv0);
        stage_write(pb + 2, cv1);
        stage_write(pb + 4, cv2);
        if (nnext == 64) stage_write(pb + 6, cv3);
      }
    }
    __syncthreads();
  };

  process(IC<64>{}, 0, 64);
  process(IC<64>{}, 1, 64);
  process(IC<64>{}, 2, 48);
  process(IC<48>{}, 3, 0);

  // ---- softmax over 225 logits
  float vv = (tid < SS_) ? sm[tid] : -1e30f;
  float m = vv;
#pragma unroll
  for (int off = 32; off >= 1; off >>= 1) m = fmaxf(m, __shfl_xor(m, off));
  if (lane == 0) red[wvs] = m;
  __syncthreads();
  m = red[0];
#pragma unroll
  for (int w = 1; w < 8; ++w) m = fmaxf(m, red[w]);
  float e = (tid < SS_) ? __expf(vv - m) : 0.f;
  float ss = e;
#pragma unroll
  for (int off = 32; off >= 1; off >>= 1) ss += __shfl_xor(ss, off);
  __syncthreads();
  if (lane == 0) red[wvs] = ss;
  __syncthreads();
  float Stot = red[0];
#pragma unroll
  for (int w = 1; w < 8; ++w) Stot += red[w];
  if (tid < SS_) sm[tid] = e / Stot;
  __syncthreads();

  // ---- weighted channel sum: 2 channels/thread (f16 features), 4-way pos split
  {
    const int c2 = (tid & 127) * 2;
    const int q  = tid >> 7;
    float accx = 0.f, accy = 0.f;
    for (int s = q; s < SS_; s += 4) {
      h2 ft = *(const h2*)(inarrh + ((size_t)rowoff[s] << 8) + c2);
      float w = sm[s];
      accx = fmaf(w, (float)ft[0], accx);
      accy = fmaf(w, (float)ft[1], accy);
    }
    __syncthreads();
    ldsf[q * 256 + c2]     = accx;
    ldsf[q * 256 + c2 + 1] = accy;
    __syncthreads();
    if (tid < 256) {
      float tot = ldsf[tid] + ldsf[256 + tid] + ldsf[512 + tid] + ldsf[768 + tid];
      if (!is_t) out[2048 + ((size_t)(b * 256 + tid) * 17 + u) * 17 + v] = tot;
      else       out[b * 256 + tid] = tot;
    }
  }
}

// ---------------------------------------------------------------------------
extern "C" void kernel_launch(void* const* d_in, const int* in_sizes, int n_in,
                              void* d_out, int out_size, void* d_ws, size_t ws_size,
                              hipStream_t stream)
{
  const float* templ = (const float*)d_in[0];
  const float* cand  = (const float*)d_in[1];
  const float* w0 = (const float*)d_in[2];
  const float* w1 = (const float*)d_in[3];
  const float* w2 = (const float*)d_in[4];
  const float* w3 = (const float*)d_in[5];
  const float* w4 = (const float*)d_in[6];
  const float* w5 = (const float*)d_in[7];
  const float* w6 = (const float*)d_in[8];

  float* ws    = (float*)d_ws;
  float* gout  = ws + OFF_GOUT;
  float* rows  = ws + OFF_ROWS;
  float* m0v   = ws + OFF_M0;
  float* tm0v  = ws + OFF_TM0;
  half_t* inarrh = (half_t*)(ws + OFF_F16);
  half_t* conv1h = inarrh + (size_t)NROW * 256;
  half_t* w0h  = conv1h + (size_t)NROW * 256;
  half_t* w1h  = w0h + NW0H;
  half_t* w2h  = w1h + 128 * 256;
  half_t* w3h  = w2h + 64 * 128;
  float* outf  = (float*)d_out;

  prep_kernel<<<NFEATB + 88, 256, 0, stream>>>(templ, cand, w0, w1, w2, w3,
                                               inarrh, w0h, w1h, w2h, w3h);
  l0gemm_kernel<<<NROW / 16, 512, 0, stream>>>(inarrh, w0h, conv1h, gout);
  rowsum_kernel<<<B_ * 31 * 17, 256, 0, stream>>>(gout, rows);
  colsum_tmean_kernel<<<B_ * KK_ + B_, 256, 0, stream>>>(rows, gout, m0v, tm0v);
  chain_kernel<<<B_ * KK_ + B_, 512, 0, stream>>>(conv1h, m0v, tm0v,
                                                  w1h, w2h, w3h, w4, w5, w6,
                                                  inarrh, outf);
}